// Round 1
// baseline (47.659 us; speedup 1.0000x reference)
//
#include <hip/hip_runtime.h>
#include <hip/hip_bf16.h>

#define F_FIELDS 39
#define VOCAB    100000
#define EMB      16
#define BATCH    16384
#define H1       32
#define H2       32
#define D_IN     (F_FIELDS*EMB)   /* 624 */
#define KSTEPS   20               /* K padded to 640 = 20 x 32 */

typedef __bf16 bf16x8 __attribute__((ext_vector_type(8)));
typedef float  f32x4  __attribute__((ext_vector_type(4)));

// Block: 256 threads = 4 waves; each wave owns 16 samples (64 samples/block).
// Lane mapping inside a wave matches the mfma_f32_16x16x32_bf16 A-fragment:
//   sample (row)  = lane & 15
//   k-window      = (lane>>4)*8 .. +7   (k = field*16 + pos; field = 2*kstep + (q>>1), pos = (q&1)*8 + j)
__global__ __launch_bounds__(256) void deepfm_kernel(
    const int*   __restrict__ Xi,  const float* __restrict__ Xv,
    const float* __restrict__ emb1,const float* __restrict__ emb2,
    const float* __restrict__ W1,  const float* __restrict__ b1,
    const float* __restrict__ W2,  const float* __restrict__ b2,
    const float* __restrict__ bias,float* __restrict__ out)
{
    __shared__ __align__(16) __bf16 W1s[KSTEPS*2*64*8]; // 40 KB, MFMA-B fragment order
    __shared__ float W2s[H1*H2];                        // 4 KB
    __shared__ float hbuf[64*33];                       // 8.4 KB, padded stride 33 (bank-conflict-free)
    __shared__ float scal[64];                          // fm + first per sample

    const int t   = threadIdx.x;
    const int blk = blockIdx.x;

    // ---- stage W2 (f32) ----
    reinterpret_cast<float4*>(W2s)[t] = reinterpret_cast<const float4*>(W2)[t];

    // ---- stage W1 (bf16) pre-swizzled into B-fragment order ----
    // frag id = (kstep*2 + nhalf)*64 + lane; element j: k = kstep*32 + (lane>>4)*8 + j, n = nhalf*16 + (lane&15)
    for (int fidx = t; fidx < KSTEPS*2*64; fidx += 256) {
        int lane = fidx & 63;
        int nh   = (fidx >> 6) & 1;
        int ks   = fidx >> 7;
        int k0   = ks*32 + (lane>>4)*8;
        int n    = nh*16 + (lane & 15);
        __bf16 vals[8];
        #pragma unroll
        for (int j = 0; j < 8; ++j) {
            int k = k0 + j;
            float v = (k < D_IN) ? W1[k*H1 + n] : 0.0f;
            vals[j] = (__bf16)v;
        }
        *reinterpret_cast<bf16x8*>(&W1s[fidx*8]) = *reinterpret_cast<const bf16x8*>(vals);
    }
    __syncthreads();

    // ---- phase A: gather + FM (f32 exact) + layer-1 MFMA (bf16) ----
    const int wave = t >> 6;
    const int l    = t & 63;
    const int sloc = l & 15;
    const int q    = l >> 4;
    const int fpar = q >> 1;          // 0: even fields, 1: odd fields
    const int eoff = (q & 1) * 8;     // position window within the 16-wide embedding
    const int sample = blk*64 + wave*16 + sloc;

    f32x4 acc0 = {0.f,0.f,0.f,0.f}, acc1 = {0.f,0.f,0.f,0.f};
    float sa[8], sq[8];
    #pragma unroll
    for (int j = 0; j < 8; ++j) { sa[j] = 0.f; sq[j] = 0.f; }

    for (int ks = 0; ks < KSTEPS; ++ks) {
        int f      = 2*ks + fpar;
        bool valid = (f < F_FIELDS);
        int  fi    = valid ? f : 0;              // safe in-bounds substitute; xv=0 kills it
        int  idx   = Xi[sample*F_FIELDS + fi];
        float xv   = valid ? Xv[sample*F_FIELDS + fi] : 0.0f;

        const float* rp = emb2 + ((size_t)fi*VOCAB + (size_t)idx)*EMB + eoff;
        float4 v0 = reinterpret_cast<const float4*>(rp)[0];
        float4 v1 = reinterpret_cast<const float4*>(rp)[1];

        float e[8] = { v0.x*xv, v0.y*xv, v0.z*xv, v0.w*xv,
                       v1.x*xv, v1.y*xv, v1.z*xv, v1.w*xv };
        bf16x8 a;
        #pragma unroll
        for (int j = 0; j < 8; ++j) {
            a[j] = (__bf16)e[j];
            sa[j] += e[j];
            sq[j] += e[j]*e[j];
        }
        bf16x8 bf0 = *reinterpret_cast<const bf16x8*>(&W1s[((ks*2+0)*64 + l)*8]);
        bf16x8 bf1 = *reinterpret_cast<const bf16x8*>(&W1s[((ks*2+1)*64 + l)*8]);
        acc0 = __builtin_amdgcn_mfma_f32_16x16x32_bf16(a, bf0, acc0, 0, 0, 0);
        acc1 = __builtin_amdgcn_mfma_f32_16x16x32_bf16(a, bf1, acc1, 0, 0, 0);
    }

    // ---- FM second-order: s and sq need the lane^32 partner (other field parity) ----
    float fmp = 0.f;
    #pragma unroll
    for (int j = 0; j < 8; ++j) {
        float sf = sa[j] + __shfl_xor(sa[j], 32);
        float qf = sq[j] + __shfl_xor(sq[j], 32);
        fmp += 0.5f*(sf*sf - qf);
    }
    fmp += __shfl_xor(fmp, 16);   // combine the two 8-wide k windows

    // ---- first-order (emb1) ----
    float facc = 0.f;
    for (int f = q; f < F_FIELDS; f += 4) {
        int idx = Xi[sample*F_FIELDS + f];
        facc += emb1[(size_t)f*VOCAB + idx] * Xv[sample*F_FIELDS + f];
    }
    facc += __shfl_xor(facc, 16);
    facc += __shfl_xor(facc, 32);
    if (l < 16) scal[wave*16 + sloc] = fmp + facc;

    // ---- layer-1 epilogue: relu(hpre + b1) -> LDS ----
    // C layout: col = lane&15, row = (lane>>4)*4 + reg
    float b1a = b1[l & 15];
    float b1b = b1[16 + (l & 15)];
    #pragma unroll
    for (int r = 0; r < 4; ++r) {
        int row = q*4 + r;
        hbuf[(wave*16 + row)*33 + (l & 15)]      = fmaxf(acc0[r] + b1a, 0.f);
        hbuf[(wave*16 + row)*33 + 16 + (l & 15)] = fmaxf(acc1[r] + b1b, 0.f);
    }
    __syncthreads();

    // ---- layer 2 (f32) + final sum ----
    const int s  = t >> 2;     // 4 threads per sample
    const int r4 = t & 3;      // each owns 8 output cols
    float acc8[8];
    #pragma unroll
    for (int u = 0; u < 8; ++u) acc8[u] = b2[r4*8 + u];
    #pragma unroll
    for (int i = 0; i < H1; ++i) {
        float hv = hbuf[s*33 + i];
        const float* wr = &W2s[i*H2 + r4*8];
        #pragma unroll
        for (int u = 0; u < 8; ++u) acc8[u] += hv * wr[u];
    }
    float psum = 0.f;
    #pragma unroll
    for (int u = 0; u < 8; ++u) psum += fmaxf(acc8[u], 0.f);
    psum += __shfl_xor(psum, 1);
    psum += __shfl_xor(psum, 2);
    if (r4 == 0) out[blk*64 + s] = psum + scal[s] + bias[0];
}

extern "C" void kernel_launch(void* const* d_in, const int* in_sizes, int n_in,
                              void* d_out, int out_size, void* d_ws, size_t ws_size,
                              hipStream_t stream) {
    const int*   Xi   = (const int*)  d_in[0];
    const float* Xv   = (const float*)d_in[1];
    const float* emb1 = (const float*)d_in[2];
    const float* emb2 = (const float*)d_in[3];
    const float* W1   = (const float*)d_in[4];
    const float* b1   = (const float*)d_in[5];
    const float* W2   = (const float*)d_in[6];
    const float* b2   = (const float*)d_in[7];
    const float* bias = (const float*)d_in[8];
    float* out = (float*)d_out;

    deepfm_kernel<<<BATCH/64, 256, 0, stream>>>(Xi, Xv, emb1, emb2, W1, b1, W2, b2, bias, out);
}

// Round 2
// 35.437 us; speedup vs baseline: 1.3449x; 1.3449x over previous
//
#include <hip/hip_runtime.h>
#include <hip/hip_bf16.h>

#define F_FIELDS 39
#define VOCAB    100000
#define EMB      16
#define BATCH    16384
#define H1       32
#define H2       32
#define KSTEPS   20   /* K = 640 = 20 x 32 */
#define KPW      10   /* k-steps per wave (2-way split) */

typedef __bf16 bf16x8 __attribute__((ext_vector_type(8)));
typedef float  f32x4  __attribute__((ext_vector_type(4)));

// ---------------- pre-kernel: W1 (f32, [624][32]) -> bf16 MFMA-B fragments in d_ws ----------------
// frag id = (kstep*2 + nhalf)*64 + lane; element j: k = kstep*32 + (lane>>4)*8 + j, n = nhalf*16 + (lane&15)
__global__ __launch_bounds__(256) void swizzle_w1_kernel(const float* __restrict__ W1,
                                                         __bf16* __restrict__ ws)
{
    int fidx = blockIdx.x * 256 + threadIdx.x;
    if (fidx >= KSTEPS * 2 * 64) return;
    int lane = fidx & 63;
    int nh   = (fidx >> 6) & 1;
    int ks   = fidx >> 7;
    int k0   = ks * 32 + (lane >> 4) * 8;
    int n    = nh * 16 + (lane & 15);
    __bf16 vals[8];
    #pragma unroll
    for (int j = 0; j < 8; ++j) {
        int k = k0 + j;
        vals[j] = (k < F_FIELDS * EMB) ? (__bf16)W1[k * H1 + n] : (__bf16)0.0f;
    }
    *reinterpret_cast<bf16x8*>(&ws[fidx * 8]) = *reinterpret_cast<const bf16x8*>(vals);
}

// ---------------- main kernel ----------------
// Block = 128 threads = 2 waves = one group of 16 samples, K split by k-step parity across waves.
// Lane map (wave h): sample = lane&15; q = lane>>4; fpar = q>>1; eoff = (q&1)*8.
//   field f = 4*ks' + 2*h + fpar  (ks' = 0..9); in-embedding pos = eoff + j.
// A-frag: row = lane&15, k = (lane>>4)*8 + j  (k-chunk = kstep*32).
// C-frag: sample row = (lane>>4)*4 + reg, col n = lane&15.
__global__ __launch_bounds__(128, 2) void deepfm_main(
    const int*   __restrict__ Xi,  const float* __restrict__ Xv,
    const float* __restrict__ emb1,const float* __restrict__ emb2,
    const __bf16* __restrict__ wsW1,
    const float* __restrict__ b1,  const float* __restrict__ W2,
    const float* __restrict__ b2,  const float* __restrict__ bias,
    float* __restrict__ out)
{
    __shared__ float pacc[2][16][32];   // per-wave partial layer-1 pre-acts
    __shared__ float sbuf[2][16][16];   // per-wave partial FM s-vector
    __shared__ float qbuf[2][16];       // per-wave partial FM sq-sum (scalar/sample)
    __shared__ float fbuf[2][16];       // per-wave partial first-order
    __shared__ float W2s[H1 * H2];      // 4 KB

    const int t    = threadIdx.x;
    const int h    = t >> 6;          // wave id = k-step parity
    const int l    = t & 63;
    const int sloc = l & 15;
    const int q    = l >> 4;
    const int fpar = q >> 1;
    const int eoff = (q & 1) * 8;
    const int sample = blockIdx.x * 16 + sloc;
    const int xbase  = sample * F_FIELDS;

    // stage W2 (256 float4 / 128 threads)
    #pragma unroll
    for (int i = 0; i < 2; ++i)
        reinterpret_cast<float4*>(W2s)[t + 128 * i] =
            reinterpret_cast<const float4*>(W2)[t + 128 * i];

    // ---- issue ALL index loads (main + first-order) ----
    int   idxm[KPW]; float xvm[KPW];
    #pragma unroll
    for (int ks = 0; ks < KPW; ++ks) {
        int f = 4 * ks + 2 * h + fpar;
        bool v = (f < F_FIELDS);
        int fi = v ? f : 0;
        idxm[ks] = Xi[xbase + fi];
        xvm[ks]  = v ? Xv[xbase + fi] : 0.0f;
    }
    int idxf[5]; float xvf[5];
    #pragma unroll
    for (int i = 0; i < 5; ++i) {
        int f = h * 4 + q + 8 * i;
        bool v = (f < F_FIELDS);
        int fi = v ? f : 0;
        idxf[i] = Xi[xbase + fi];
        xvf[i]  = v ? Xv[xbase + fi] : 0.0f;
    }

    // ---- issue all gathers + fragment loads (deep MLP: ~45 loads in flight) ----
    float4 g0[KPW], g1[KPW];
    bf16x8 fr0[KPW], fr1[KPW];
    const bf16x8* wsf = reinterpret_cast<const bf16x8*>(wsW1);
    #pragma unroll
    for (int ks = 0; ks < KPW; ++ks) {
        int f = 4 * ks + 2 * h + fpar;
        int fi = (f < F_FIELDS) ? f : 0;
        int off = (fi * VOCAB + idxm[ks]) * EMB + eoff;   // < 2^26, int ok
        const float4* rp = reinterpret_cast<const float4*>(emb2 + off);
        g0[ks] = rp[0];
        g1[ks] = rp[1];
        int kstep = 2 * ks + h;
        fr0[ks] = wsf[(kstep * 2 + 0) * 64 + l];
        fr1[ks] = wsf[(kstep * 2 + 1) * 64 + l];
    }
    float e1v[5];
    #pragma unroll
    for (int i = 0; i < 5; ++i) {
        int f = h * 4 + q + 8 * i;
        int fi = (f < F_FIELDS) ? f : 0;
        e1v[i] = emb1[fi * VOCAB + idxf[i]];
    }

    // ---- consume: FM stats + layer-1 MFMA ----
    f32x4 acc0 = {0.f,0.f,0.f,0.f}, acc1 = {0.f,0.f,0.f,0.f};
    float sa[8], sq[8];
    #pragma unroll
    for (int j = 0; j < 8; ++j) { sa[j] = 0.f; sq[j] = 0.f; }

    #pragma unroll
    for (int ks = 0; ks < KPW; ++ks) {
        float xv = xvm[ks];
        float e[8] = { g0[ks].x*xv, g0[ks].y*xv, g0[ks].z*xv, g0[ks].w*xv,
                       g1[ks].x*xv, g1[ks].y*xv, g1[ks].z*xv, g1[ks].w*xv };
        bf16x8 a;
        #pragma unroll
        for (int j = 0; j < 8; ++j) {
            a[j] = (__bf16)e[j];
            sa[j] += e[j];
            sq[j] += e[j]*e[j];
        }
        acc0 = __builtin_amdgcn_mfma_f32_16x16x32_bf16(a, fr0[ks], acc0, 0, 0, 0);
        acc1 = __builtin_amdgcn_mfma_f32_16x16x32_bf16(a, fr1[ks], acc1, 0, 0, 0);
    }

    // ---- FM in-wave reduce: combine field-parity (lane^32) ----
    float sf[8];
    float qq = 0.f;
    #pragma unroll
    for (int j = 0; j < 8; ++j) {
        sf[j] = sa[j] + __shfl_xor(sa[j], 32);
        qq   += sq[j];
    }
    qq += __shfl_xor(qq, 32);
    qq += __shfl_xor(qq, 16);
    if (q < 2) {
        float4 v0 = make_float4(sf[0], sf[1], sf[2], sf[3]);
        float4 v1 = make_float4(sf[4], sf[5], sf[6], sf[7]);
        float4* srow = reinterpret_cast<float4*>(&sbuf[h][sloc][q * 8]);
        srow[0] = v0; srow[1] = v1;
    }
    if (l < 16) qbuf[h][sloc] = qq;

    // ---- first-order finish ----
    float facc = 0.f;
    #pragma unroll
    for (int i = 0; i < 5; ++i) facc += e1v[i] * xvf[i];
    facc += __shfl_xor(facc, 16);
    facc += __shfl_xor(facc, 32);
    if (l < 16) fbuf[h][sloc] = facc;

    // ---- layer-1 partials -> LDS (b1 folded into wave 0's copy) ----
    float badd0 = (h == 0) ? b1[sloc]      : 0.f;
    float badd1 = (h == 0) ? b1[16 + sloc] : 0.f;
    #pragma unroll
    for (int r = 0; r < 4; ++r) {
        int row = q * 4 + r;
        pacc[h][row][sloc]      = acc0[r] + badd0;
        pacc[h][row][16 + sloc] = acc1[r] + badd1;
    }
    __syncthreads();

    // ---- final phase: 8 threads per sample ----
    const int s = t >> 3;
    const int u = t & 7;

    // FM: sum of squares of full s-vector (2 positions per thread)
    float s2 = 0.f;
    #pragma unroll
    for (int p = 0; p < 2; ++p) {
        int pos = u * 2 + p;
        float sv = sbuf[0][s][pos] + sbuf[1][s][pos];
        s2 += sv * sv;
    }

    // layer 2: 4 output cols per thread
    float a4[4];
    #pragma unroll
    for (int c = 0; c < 4; ++c) a4[c] = b2[u * 4 + c];
    #pragma unroll
    for (int i = 0; i < H1; ++i) {
        float hv = fmaxf(pacc[0][s][i] + pacc[1][s][i], 0.f);
        const float* wr = &W2s[i * H2 + u * 4];
        #pragma unroll
        for (int c = 0; c < 4; ++c) a4[c] += hv * wr[c];
    }
    float psum = 0.f;
    #pragma unroll
    for (int c = 0; c < 4; ++c) psum += fmaxf(a4[c], 0.f);

    // reduce across the 8 threads of this sample (contiguous lanes)
    psum += __shfl_xor(psum, 1);
    psum += __shfl_xor(psum, 2);
    psum += __shfl_xor(psum, 4);
    s2   += __shfl_xor(s2, 1);
    s2   += __shfl_xor(s2, 2);
    s2   += __shfl_xor(s2, 4);

    if (u == 0) {
        float qtot = qbuf[0][s] + qbuf[1][s];
        float ftot = fbuf[0][s] + fbuf[1][s];
        out[blockIdx.x * 16 + s] = psum + 0.5f * (s2 - qtot) + ftot + bias[0];
    }
}

extern "C" void kernel_launch(void* const* d_in, const int* in_sizes, int n_in,
                              void* d_out, int out_size, void* d_ws, size_t ws_size,
                              hipStream_t stream) {
    const int*   Xi   = (const int*)  d_in[0];
    const float* Xv   = (const float*)d_in[1];
    const float* emb1 = (const float*)d_in[2];
    const float* emb2 = (const float*)d_in[3];
    const float* W1   = (const float*)d_in[4];
    const float* b1   = (const float*)d_in[5];
    const float* W2   = (const float*)d_in[6];
    const float* b2   = (const float*)d_in[7];
    const float* bias = (const float*)d_in[8];
    float* out = (float*)d_out;
    __bf16* ws = (__bf16*)d_ws;

    swizzle_w1_kernel<<<(KSTEPS*2*64 + 255)/256, 256, 0, stream>>>(W1, ws);
    deepfm_main<<<BATCH/16, 128, 0, stream>>>(Xi, Xv, emb1, emb2, ws, b1, W2, b2, bias, out);
}

// Round 3
// 34.622 us; speedup vs baseline: 1.3766x; 1.0236x over previous
//
#include <hip/hip_runtime.h>
#include <hip/hip_bf16.h>

#define F_FIELDS 39
#define VOCAB    100000
#define EMB      16
#define BATCH    16384
#define H1       32
#define H2       32
#define KSTEPS   20   /* K = 640 = 20 x 32 */
#define KPW      5    /* k-steps per wave (4-way K-split) */

typedef __bf16 bf16x8 __attribute__((ext_vector_type(8)));
typedef float  f32x4  __attribute__((ext_vector_type(4)));

// ---------------- pre-kernel: W1 (f32, [624][32]) -> bf16 MFMA-B fragments in d_ws ----------------
// frag id = (kstep*2 + nhalf)*64 + lane; element j: k = kstep*32 + (lane>>4)*8 + j, n = nhalf*16 + (lane&15)
__global__ __launch_bounds__(256) void swizzle_w1_kernel(const float* __restrict__ W1,
                                                         __bf16* __restrict__ ws)
{
    int fidx = blockIdx.x * 256 + threadIdx.x;
    if (fidx >= KSTEPS * 2 * 64) return;
    int lane = fidx & 63;
    int nh   = (fidx >> 6) & 1;
    int ks   = fidx >> 7;
    int k0   = ks * 32 + (lane >> 4) * 8;
    int n    = nh * 16 + (lane & 15);
    __bf16 vals[8];
    #pragma unroll
    for (int j = 0; j < 8; ++j) {
        int k = k0 + j;
        vals[j] = (k < F_FIELDS * EMB) ? (__bf16)W1[k * H1 + n] : (__bf16)0.0f;
    }
    *reinterpret_cast<bf16x8*>(&ws[fidx * 8]) = *reinterpret_cast<const bf16x8*>(vals);
}

// ---------------- main kernel ----------------
// Block = 256 threads = 4 waves = one group of 16 samples; K split 4-way by wave.
// Wave h owns k-steps kstep = 4*ks' + h (ks' = 0..4).
// Lane map: sample = lane&15; q = lane>>4; fpar = q>>1; eoff = (q&1)*8.
//   field f = 2*kstep + fpar = 8*ks' + 2*h + fpar   (f == 39 masked via xv=0)
// A-frag: row = lane&15, k_local = q*8 + j.   C-frag: row = q*4 + reg, col = lane&15.
__global__ __launch_bounds__(256, 4) void deepfm_main(
    const int*   __restrict__ Xi,  const float* __restrict__ Xv,
    const float* __restrict__ emb1,const float* __restrict__ emb2,
    const __bf16* __restrict__ wsW1,
    const float* __restrict__ b1,  const float* __restrict__ W2,
    const float* __restrict__ b2,  const float* __restrict__ bias,
    float* __restrict__ out)
{
    __shared__ int   sXi[16 * F_FIELDS];   // 2.4 KB
    __shared__ float sXv[16 * F_FIELDS];   // 2.4 KB
    __shared__ float pacc[4][16][32];      // 8 KB   per-wave layer-1 partials
    __shared__ float sbuf[4][16][16];      // 4 KB   per-wave FM s-vector partials
    __shared__ float qbuf[4][16];          // per-wave FM sq-sum partials
    __shared__ float fbuf[4][16];          // per-wave first-order partials
    __shared__ float W2s[H1 * H2];         // 4 KB
    __shared__ float hs[16][32];           // 2 KB   relu(layer-1)

    const int t    = threadIdx.x;
    const int h    = t >> 6;           // wave id (k-split)
    const int l    = t & 63;
    const int sloc = l & 15;
    const int q    = l >> 4;
    const int fpar = q >> 1;
    const int eoff = (q & 1) * 8;
    const int blk  = blockIdx.x;

    // ---- coalesced stage of this block's Xi/Xv rows (16 samples x 39, contiguous) ----
    {
        const int base = blk * 16 * F_FIELDS;
        #pragma unroll
        for (int i = t; i < 16 * F_FIELDS; i += 256) {
            sXi[i] = Xi[base + i];
            sXv[i] = Xv[base + i];
        }
    }
    // stage W2 (256 float4 / 256 threads)
    reinterpret_cast<float4*>(W2s)[t] = reinterpret_cast<const float4*>(W2)[t];
    __syncthreads();

    // ---- gather issue: 10 float4 loads per lane ----
    float xvm[KPW];
    float4 g0[KPW], g1[KPW];
    #pragma unroll
    for (int ks = 0; ks < KPW; ++ks) {
        int f = 8 * ks + 2 * h + fpar;
        bool v = (f < F_FIELDS);
        int fi = v ? f : 0;
        int idx = sXi[sloc * F_FIELDS + fi];
        xvm[ks] = v ? sXv[sloc * F_FIELDS + fi] : 0.0f;
        const float4* rp = reinterpret_cast<const float4*>(emb2 + (fi * VOCAB + idx) * EMB + eoff);
        g0[ks] = rp[0];
        g1[ks] = rp[1];
    }
    // first-order gathers: fields f = (4h+q) + 16*i
    float e1v[3]; float xvf[3];
    #pragma unroll
    for (int i = 0; i < 3; ++i) {
        int f = 4 * h + q + 16 * i;
        bool v = (f < F_FIELDS);
        int fi = v ? f : 0;
        int idx = sXi[sloc * F_FIELDS + fi];
        xvf[i] = v ? sXv[sloc * F_FIELDS + fi] : 0.0f;
        e1v[i] = emb1[fi * VOCAB + idx];
    }

    // ---- consume: FM stats + layer-1 MFMA (frags straight from L2) ----
    const bf16x8* wsf = reinterpret_cast<const bf16x8*>(wsW1);
    f32x4 acc0 = {0.f,0.f,0.f,0.f}, acc1 = {0.f,0.f,0.f,0.f};
    float sa[8];
    float qq = 0.f;
    #pragma unroll
    for (int j = 0; j < 8; ++j) sa[j] = 0.f;

    #pragma unroll
    for (int ks = 0; ks < KPW; ++ks) {
        int kstep = 4 * ks + h;
        bf16x8 fr0 = wsf[(kstep * 2 + 0) * 64 + l];
        bf16x8 fr1 = wsf[(kstep * 2 + 1) * 64 + l];
        float xv = xvm[ks];
        float e[8] = { g0[ks].x*xv, g0[ks].y*xv, g0[ks].z*xv, g0[ks].w*xv,
                       g1[ks].x*xv, g1[ks].y*xv, g1[ks].z*xv, g1[ks].w*xv };
        bf16x8 a;
        #pragma unroll
        for (int j = 0; j < 8; ++j) {
            a[j] = (__bf16)e[j];
            sa[j] += e[j];
            qq   += e[j]*e[j];
        }
        acc0 = __builtin_amdgcn_mfma_f32_16x16x32_bf16(a, fr0, acc0, 0, 0, 0);
        acc1 = __builtin_amdgcn_mfma_f32_16x16x32_bf16(a, fr1, acc1, 0, 0, 0);
    }

    // ---- FM partial reduce within wave: combine field parity (lane^32, same eoff) ----
    float sf[8];
    #pragma unroll
    for (int j = 0; j < 8; ++j) sf[j] = sa[j] + __shfl_xor(sa[j], 32);
    qq += __shfl_xor(qq, 32);
    qq += __shfl_xor(qq, 16);
    if (q < 2) {   // q=0 -> positions 0..7 (eoff 0), q=1 -> positions 8..15 (eoff 8)
        float4* srow = reinterpret_cast<float4*>(&sbuf[h][sloc][q * 8]);
        srow[0] = make_float4(sf[0], sf[1], sf[2], sf[3]);
        srow[1] = make_float4(sf[4], sf[5], sf[6], sf[7]);
    }
    if (l < 16) qbuf[h][sloc] = qq;

    // ---- first-order partial ----
    float facc = 0.f;
    #pragma unroll
    for (int i = 0; i < 3; ++i) facc += e1v[i] * xvf[i];
    facc += __shfl_xor(facc, 16);
    facc += __shfl_xor(facc, 32);
    if (l < 16) fbuf[h][sloc] = facc;

    // ---- layer-1 partials -> LDS (b1 folded into wave 0) ----
    float badd0 = (h == 0) ? b1[sloc]      : 0.f;
    float badd1 = (h == 0) ? b1[16 + sloc] : 0.f;
    #pragma unroll
    for (int r = 0; r < 4; ++r) {
        int row = q * 4 + r;
        pacc[h][row][sloc]      = acc0[r] + badd0;
        pacc[h][row][16 + sloc] = acc1[r] + badd1;
    }
    __syncthreads();

    // ---- h = relu(sum of partials): 512 values, 2 per thread ----
    {
        int s = t >> 4, c = t & 15;
        hs[s][c]      = fmaxf(pacc[0][s][c]      + pacc[1][s][c]      + pacc[2][s][c]      + pacc[3][s][c],      0.f);
        hs[s][c + 16] = fmaxf(pacc[0][s][c + 16] + pacc[1][s][c + 16] + pacc[2][s][c + 16] + pacc[3][s][c + 16], 0.f);
    }
    __syncthreads();

    // ---- final: 16 threads per sample ----
    const int s = t >> 4;
    const int u = t & 15;

    // FM: position u of the full s-vector
    float sv = sbuf[0][s][u] + sbuf[1][s][u] + sbuf[2][s][u] + sbuf[3][s][u];
    float s2 = sv * sv;

    // layer 2: cols 2u, 2u+1
    float a0 = b2[2 * u], a1 = b2[2 * u + 1];
    #pragma unroll
    for (int i = 0; i < H1; ++i) {
        float hv = hs[s][i];
        a0 += hv * W2s[i * H2 + 2 * u];
        a1 += hv * W2s[i * H2 + 2 * u + 1];
    }
    float psum = fmaxf(a0, 0.f) + fmaxf(a1, 0.f);

    psum += __shfl_xor(psum, 1);  s2 += __shfl_xor(s2, 1);
    psum += __shfl_xor(psum, 2);  s2 += __shfl_xor(s2, 2);
    psum += __shfl_xor(psum, 4);  s2 += __shfl_xor(s2, 4);
    psum += __shfl_xor(psum, 8);  s2 += __shfl_xor(s2, 8);

    if (u == 0) {
        float qtot = qbuf[0][s] + qbuf[1][s] + qbuf[2][s] + qbuf[3][s];
        float ftot = fbuf[0][s] + fbuf[1][s] + fbuf[2][s] + fbuf[3][s];
        out[blk * 16 + s] = psum + 0.5f * (s2 - qtot) + ftot + bias[0];
    }
}

extern "C" void kernel_launch(void* const* d_in, const int* in_sizes, int n_in,
                              void* d_out, int out_size, void* d_ws, size_t ws_size,
                              hipStream_t stream) {
    const int*   Xi   = (const int*)  d_in[0];
    const float* Xv   = (const float*)d_in[1];
    const float* emb1 = (const float*)d_in[2];
    const float* emb2 = (const float*)d_in[3];
    const float* W1   = (const float*)d_in[4];
    const float* b1   = (const float*)d_in[5];
    const float* W2   = (const float*)d_in[6];
    const float* b2   = (const float*)d_in[7];
    const float* bias = (const float*)d_in[8];
    float* out = (float*)d_out;
    __bf16* ws = (__bf16*)d_ws;

    swizzle_w1_kernel<<<(KSTEPS*2*64 + 255)/256, 256, 0, stream>>>(W1, ws);
    deepfm_main<<<BATCH/16, 256, 0, stream>>>(Xi, Xv, emb1, emb2, ws, b1, W2, b2, bias, out);
}